// Round 6
// baseline (426.275 us; speedup 1.0000x reference)
//
#include <hip/hip_runtime.h>
#include <hip/hip_bf16.h>
#include <stdint.h>

#define T_ROWS 131072
#define GCNT   64
#define KDIM   1024
#define NDIM   512
#define BM     128
#define BN     128
#define BK     64
#define KTILES (KDIM / BK)     // 16
#define MT_MAX 1088            // upper bound on 128-row tiles
#define NBLK   (MT_MAX * 4)    // 4352 blocks, /8 = 544 (XCD swizzle exact)

typedef __attribute__((ext_vector_type(4))) float f32x4;
typedef __attribute__((ext_vector_type(8))) short s16x8;
typedef __attribute__((ext_vector_type(4))) short s16x4;
typedef __attribute__((address_space(3))) unsigned int lds_u32;
typedef const __attribute__((address_space(1))) unsigned int gbl_u32;

static __device__ __forceinline__ short f2bf(float f) {
  __hip_bfloat16 h = __float2bfloat16(f);
  return __builtin_bit_cast(short, h);
}

// ---------------------------------------------------------------------------
// Pre-pass: b [G][K][N] fp32 -> bt: per (g, nt128, kt) 16KB bf16 tile images,
// layout [G][4][16][16384B]. Image byte for B[k][n] (k in [0,64), n in
// [0,128)):  n*128 + (((k>>3) ^ (n&7))<<4) + (k&7)*2   (bank swizzle baked).
// ---------------------------------------------------------------------------
__global__ __launch_bounds__(256) void bt_kernel(const float* __restrict__ b,
                                                 char* __restrict__ bt) {
  __shared__ short lt[64 * 130];
  int bid = blockIdx.x;               // g*64 + nt*16 + kt
  int kt = bid & 15, nt = (bid >> 4) & 3, g = bid >> 6;
  int t = threadIdx.x;
  const float* src = b + ((size_t)(g * KDIM + kt * BK)) * NDIM + nt * 128;
#pragma unroll
  for (int i = 0; i < 32; i++) {
    int idx = i * 256 + t;
    int kk = idx >> 7, nn = idx & 127;
    lt[kk * 130 + nn] = f2bf(src[(size_t)kk * NDIM + nn]);
  }
  __syncthreads();
  char* dst = bt + ((size_t)bid << 14);
#pragma unroll
  for (int j = 0; j < 4; j++) {
    int chunk = j * 256 + t;
    int n = chunk >> 3;
    int slot = (chunk & 7) ^ (n & 7);
    s16x8 v;
#pragma unroll
    for (int i = 0; i < 8; i++) v[i] = lt[(slot * 8 + i) * 130 + n];
    *(s16x8*)(dst + (size_t)chunk * 16) = v;
  }
}

// ---------------------------------------------------------------------------
// Grouped GEMM: 128x128 tile, 4 waves (2x2), BK=64, double-buffered 64 KB LDS
// -> 2 blocks/CU. Simple 2-phase schedule (one barrier per K-tile); the other
// resident block covers each block's barrier/drain stalls (implicit overlap).
// B via global_load_lds from pre-swizzled bt; A fp32 reg-staged -> bf16.
// ---------------------------------------------------------------------------
__global__ __launch_bounds__(256, 2) void gemm2(
    const float* __restrict__ a, const char* __restrict__ bt,
    const int* __restrict__ sizes, const int* __restrict__ offs,
    float* __restrict__ out) {
  __shared__ __align__(16) short lds_a[2][BM * BK];     // 2 x 16 KB
  __shared__ __align__(16) char lds_b[2][BN * BK * 2];  // 2 x 16 KB

  int bid0 = blockIdx.x;
  int bid = (bid0 & 7) * (NBLK / 8) + (bid0 >> 3);  // XCD-chunked swizzle
  int bn = bid & 3;      // bn fastest: 4 blocks sharing an A panel adjacent
  int tm = bid >> 2;

  // group scan: tiles_g = padded_size_g / 128
  int g = -1, m_loc = 0, base = 0;
#pragma unroll
  for (int i = 0; i < GCNT; i++) {
    int tg = ((sizes[i] + 127) & ~127) >> 7;
    if (tm >= base && tm < base + tg) { g = i; m_loc = (tm - base) << 7; }
    base += tg;
  }
  if (g < 0) return;
  int size = sizes[g], off = offs[g], valid = size - m_loc;

  int t = threadIdx.x, lane = t & 63, wid = t >> 6;
  int wm = wid >> 1, wn = wid & 1, lr = lane & 15, q = lane >> 4;

  // A staging: chunk c = i*256 + t -> row = i*16 + (t>>4), 16B col (t&15).
  // Wave covers 4 full consecutive rows per load -> fully coalesced.
  int r0 = t >> 4, c16 = t & 15;
  int aoff[8];
#pragma unroll
  for (int i = 0; i < 8; i++) {
    int row = off + m_loc + i * 16 + r0;
    if (row >= T_ROWS) row = T_ROWS - 1;  // junk rows masked at store
    aoff[i] = row * KDIM + c16 * 4;
  }
  // LDS write byte (tile-local): row&7 == r0&7 for all i (i*16 % 8 == 0)
  int a_wbyte = r0 * 128 + (((c16 >> 1) ^ (r0 & 7)) << 4) + (c16 & 1) * 8;

  const char* btimg = bt + ((size_t)((g << 6) + (bn << 4)) << 14);

  f32x4 acc[4][4];
#pragma unroll
  for (int i = 0; i < 4; i++)
#pragma unroll
    for (int j = 0; j < 4; j++) acc[i][j] = (f32x4){0.f, 0.f, 0.f, 0.f};
  f32x4 va[8];

  auto loadA = [&](int kt) {
#pragma unroll
    for (int i = 0; i < 8; i++)
      va[i] = *(const f32x4*)(a + aoff[i] + kt * BK);
  };
  auto writeA = [&](int c) {  // compiler inserts counted vmcnt for va
    char* db = (char*)lds_a[c] + a_wbyte;
#pragma unroll
    for (int i = 0; i < 8; i++) {
      s16x4 v;
#pragma unroll
      for (int e = 0; e < 4; e++) v[e] = f2bf(va[i][e]);
      *(s16x4*)(db + i * 2048) = v;   // row step 16 -> 16*128 bytes
    }
  };
  auto stageB = [&](int kt, int c) {
#pragma unroll
    for (int i = 0; i < 4; i++) {
      int wc = wid * 4 + i;                 // wave-uniform 1KB chunk, 0..15
      int cc = wc * 64 + lane;              // 16B chunk in image
      const char* gsrc = btimg + ((size_t)kt << 14) + (size_t)cc * 16;
      __builtin_amdgcn_global_load_lds(
          (gbl_u32*)gsrc, (lds_u32*)((char*)lds_b[c] + wc * 1024), 16, 0, 0);
    }
  };
  auto compute = [&](int c) {
#pragma unroll
    for (int ks = 0; ks < 2; ks++) {
      s16x8 af[4], bf[4];
#pragma unroll
      for (int fm = 0; fm < 4; fm++) {
        int row = wm * 64 + fm * 16 + lr;
        int slot = (ks * 4 + q) ^ (row & 7);
        af[fm] = *(const s16x8*)((const char*)lds_a[c] + row * 128 + slot * 16);
      }
#pragma unroll
      for (int fn = 0; fn < 4; fn++) {
        int n = wn * 64 + fn * 16 + lr;
        int slot = (ks * 4 + q) ^ (n & 7);
        bf[fn] = *(const s16x8*)((const char*)lds_b[c] + n * 128 + slot * 16);
      }
#pragma unroll
      for (int fm = 0; fm < 4; fm++)
#pragma unroll
        for (int fn = 0; fn < 4; fn++)
          acc[fm][fn] = __builtin_amdgcn_mfma_f32_16x16x32_bf16(
              af[fm], bf[fn], acc[fm][fn], 0, 0, 0);
    }
  };

  // prologue: stage tile 0 into buf 0
  loadA(0);
  stageB(0, 0);
  writeA(0);
  __syncthreads();

  for (int kt = 0; kt < KTILES; kt++) {
    int cur = kt & 1, nxt = cur ^ 1;
    bool more = (kt + 1 < KTILES);
    if (more) {
      loadA(kt + 1);          // A fp32 loads fly during compute
      stageB(kt + 1, nxt);    // B DMA flies during compute
    }
    compute(cur);
    if (more) {
      writeA(nxt);            // waits va (counted), cvt, ds_write
      __syncthreads();        // drain covered by the co-resident block
    }
  }

  // epilogue: D frag col = lane&15, row = (lane>>4)*4 + j; masked rows
  size_t orow0 = (size_t)(off + m_loc);
#pragma unroll
  for (int fm = 0; fm < 4; fm++) {
#pragma unroll
    for (int j = 0; j < 4; j++) {
      int rm = wm * 64 + fm * 16 + q * 4 + j;
      if (rm < valid) {
        float* orow = out + (orow0 + rm) * NDIM + bn * BN + wn * 64 + lr;
#pragma unroll
        for (int fn = 0; fn < 4; fn++) orow[fn * 16] = acc[fm][fn][j];
      }
    }
  }
}

// ---------------------------------------------------------------------------
// Fallback (no workspace): same structure, B transposed in-kernel.
// ---------------------------------------------------------------------------
__global__ __launch_bounds__(256, 2) void gemm_fb(
    const float* __restrict__ a, const float* __restrict__ b,
    const int* __restrict__ sizes, const int* __restrict__ offs,
    float* __restrict__ out) {
  __shared__ __align__(16) short lds_a[2][BM * BK];
  __shared__ __align__(16) char lds_b[2][BN * BK * 2];

  int bid0 = blockIdx.x;
  int bid = (bid0 & 7) * (NBLK / 8) + (bid0 >> 3);
  int bn = bid & 3;
  int tm = bid >> 2;

  int g = -1, m_loc = 0, base = 0;
#pragma unroll
  for (int i = 0; i < GCNT; i++) {
    int tg = ((sizes[i] + 127) & ~127) >> 7;
    if (tm >= base && tm < base + tg) { g = i; m_loc = (tm - base) << 7; }
    base += tg;
  }
  if (g < 0) return;
  int size = sizes[g], off = offs[g], valid = size - m_loc;

  int t = threadIdx.x, lane = t & 63, wid = t >> 6;
  int wm = wid >> 1, wn = wid & 1, lr = lane & 15, q = lane >> 4;

  int r0 = t >> 4, c16 = t & 15;
  int aoff[8];
#pragma unroll
  for (int i = 0; i < 8; i++) {
    int row = off + m_loc + i * 16 + r0;
    if (row >= T_ROWS) row = T_ROWS - 1;
    aoff[i] = row * KDIM + c16 * 4;
  }
  int a_wbyte = r0 * 128 + (((c16 >> 1) ^ (r0 & 7)) << 4) + (c16 & 1) * 8;
  int fb_n = t >> 1, fb_kh = (t & 1) * 32;   // thread owns column fb_n

  f32x4 acc[4][4];
#pragma unroll
  for (int i = 0; i < 4; i++)
#pragma unroll
    for (int j = 0; j < 4; j++) acc[i][j] = (f32x4){0.f, 0.f, 0.f, 0.f};
  f32x4 va[8];

  auto loadA = [&](int kt) {
#pragma unroll
    for (int i = 0; i < 8; i++) va[i] = *(const f32x4*)(a + aoff[i] + kt * BK);
  };
  auto writeA = [&](int c) {
    char* db = (char*)lds_a[c] + a_wbyte;
#pragma unroll
    for (int i = 0; i < 8; i++) {
      s16x4 v;
#pragma unroll
      for (int e = 0; e < 4; e++) v[e] = f2bf(va[i][e]);
      *(s16x4*)(db + i * 2048) = v;
    }
  };
  auto stageB = [&](int kt, int c) {
    const float* p = b + (size_t)g * KDIM * NDIM +
                     (size_t)(kt * BK + fb_kh) * NDIM + bn * BN + fb_n;
    float vals[32];
#pragma unroll
    for (int i = 0; i < 32; i++) vals[i] = p[(size_t)i * NDIM];
    char* lb = (char*)lds_b[c] + fb_n * 128;
#pragma unroll
    for (int i8 = 0; i8 < 4; i8++) {
      int slot = (fb_kh >> 3) + i8;
      s16x8 v;
#pragma unroll
      for (int e = 0; e < 8; e++) v[e] = f2bf(vals[i8 * 8 + e]);
      *(s16x8*)(lb + ((slot ^ (fb_n & 7)) << 4)) = v;
    }
  };
  auto compute = [&](int c) {
#pragma unroll
    for (int ks = 0; ks < 2; ks++) {
      s16x8 af[4], bf[4];
#pragma unroll
      for (int fm = 0; fm < 4; fm++) {
        int row = wm * 64 + fm * 16 + lr;
        int slot = (ks * 4 + q) ^ (row & 7);
        af[fm] = *(const s16x8*)((const char*)lds_a[c] + row * 128 + slot * 16);
      }
#pragma unroll
      for (int fn = 0; fn < 4; fn++) {
        int n = wn * 64 + fn * 16 + lr;
        int slot = (ks * 4 + q) ^ (n & 7);
        bf[fn] = *(const s16x8*)((const char*)lds_b[c] + n * 128 + slot * 16);
      }
#pragma unroll
      for (int fm = 0; fm < 4; fm++)
#pragma unroll
        for (int fn = 0; fn < 4; fn++)
          acc[fm][fn] = __builtin_amdgcn_mfma_f32_16x16x32_bf16(
              af[fm], bf[fn], acc[fm][fn], 0, 0, 0);
    }
  };

  loadA(0);
  stageB(0, 0);
  writeA(0);
  __syncthreads();
  for (int kt = 0; kt < KTILES; kt++) {
    int cur = kt & 1, nxt = cur ^ 1;
    bool more = (kt + 1 < KTILES);
    if (more) loadA(kt + 1);
    compute(cur);
    if (more) {
      stageB(kt + 1, nxt);
      writeA(nxt);
      __syncthreads();
    }
  }
  size_t orow0 = (size_t)(off + m_loc);
#pragma unroll
  for (int fm = 0; fm < 4; fm++) {
#pragma unroll
    for (int j = 0; j < 4; j++) {
      int rm = wm * 64 + fm * 16 + q * 4 + j;
      if (rm < valid) {
        float* orow = out + (orow0 + rm) * NDIM + bn * BN + wn * 64 + lr;
#pragma unroll
        for (int fn = 0; fn < 4; fn++) orow[fn * 16] = acc[fm][fn][j];
      }
    }
  }
}

extern "C" void kernel_launch(void* const* d_in, const int* in_sizes, int n_in,
                              void* d_out, int out_size, void* d_ws,
                              size_t ws_size, hipStream_t stream) {
  const float* a = (const float*)d_in[0];
  const float* b = (const float*)d_in[1];
  const int* sizes = (const int*)d_in[2];
  const int* offs = (const int*)d_in[3];
  float* out = (float*)d_out;

  const size_t bt_bytes = (size_t)GCNT * KDIM * NDIM * 2;  // 64 MB
  if (ws_size >= bt_bytes) {
    bt_kernel<<<GCNT * 64, 256, 0, stream>>>(b, (char*)d_ws);
    gemm2<<<NBLK, 256, 0, stream>>>(a, (const char*)d_ws, sizes, offs, out);
  } else {
    gemm_fb<<<NBLK, 256, 0, stream>>>(a, b, sizes, offs, out);
  }
}

// Round 7
// 351.315 us; speedup vs baseline: 1.2134x; 1.2134x over previous
//
#include <hip/hip_runtime.h>
#include <hip/hip_bf16.h>
#include <stdint.h>

#define T_ROWS 131072
#define GCNT   64
#define KDIM   1024
#define NDIM   512
#define BM     256
#define BN     256
#define BK     64
#define KTILES (KDIM / BK)     // 16
#define MT_MAX 640             // upper bound on 256-row tiles (actual ~550)
#define NBLK   (MT_MAX * 2)    // 1280 blocks, /8 = 160 (XCD swizzle exact)

typedef __attribute__((ext_vector_type(4))) float f32x4;
typedef __attribute__((ext_vector_type(8))) short s16x8;
typedef __attribute__((ext_vector_type(4))) short s16x4;
typedef __attribute__((address_space(3))) unsigned int lds_u32;
typedef const __attribute__((address_space(1))) unsigned int gbl_u32;

static __device__ __forceinline__ short f2bf(float f) {
  __hip_bfloat16 h = __float2bfloat16(f);
  return __builtin_bit_cast(short, h);
}

// ---------------------------------------------------------------------------
// Pre-pass: b [G][K][N] fp32 -> bt: per (g, nt128, kt) 16KB bf16 tile images,
// layout [G][4][16][16384B]. Image byte for B[k][n] (k in [0,64), n in
// [0,128)):  n*128 + (((k>>3) ^ (n&7))<<4) + (k&7)*2   (bank swizzle baked).
// ---------------------------------------------------------------------------
__global__ __launch_bounds__(256) void bt_kernel(const float* __restrict__ b,
                                                 char* __restrict__ bt) {
  __shared__ short lt[64 * 130];
  int bid = blockIdx.x;               // g*64 + nt*16 + kt
  int kt = bid & 15, nt = (bid >> 4) & 3, g = bid >> 6;
  int t = threadIdx.x;
  const float* src = b + ((size_t)(g * KDIM + kt * BK)) * NDIM + nt * 128;
#pragma unroll
  for (int i = 0; i < 32; i++) {
    int idx = i * 256 + t;
    int kk = idx >> 7, nn = idx & 127;
    lt[kk * 130 + nn] = f2bf(src[(size_t)kk * NDIM + nn]);
  }
  __syncthreads();
  char* dst = bt + ((size_t)bid << 14);
#pragma unroll
  for (int j = 0; j < 4; j++) {
    int chunk = j * 256 + t;
    int n = chunk >> 3;
    int slot = (chunk & 7) ^ (n & 7);
    s16x8 v;
#pragma unroll
    for (int i = 0; i < 8; i++) v[i] = lt[(slot * 8 + i) * 130 + n];
    *(s16x8*)(dst + (size_t)chunk * 16) = v;
  }
}

// ---------------------------------------------------------------------------
// Grouped GEMM, 256x256, 8 waves, BK=64. Steady-state K-tile (UNCONDITIONAL
// main loop kt=0..13; kt=14,15 peeled):
//  ph0: dsA q0 + dsB ks0 | issue A(kt+1) h0 | BAR | 16 MFMA | BAR
//  ph1: dsA q0 + dsB ks1 | issue A(kt+1) h1 | BAR | 16 MFMA | BAR
//  ph2: dsA q1           | issue B(kt+2)->cur h0 (lds_b[cur] dead) | ...
//  ph3: dsA q1           | issue B(kt+2)->cur h1 | BAR | MFMA | BAR
//  ph4: writeA(nxt): cvt's REGISTER DEP auto-waits exactly vmcnt(4)
//       [retires B(kt+1)+A(kt+1), keeps B(kt+2) in flight]; then only
//       lgkmcnt(0) + barrier. vmcnt NEVER drains to 0 in the main loop.
// ---------------------------------------------------------------------------
__global__ __launch_bounds__(512, 2) void gemm8(
    const float* __restrict__ a, const char* __restrict__ bt,
    const int* __restrict__ sizes, const int* __restrict__ offs,
    float* __restrict__ out) {
  __shared__ __align__(16) short lds_a[2][BM * BK];     // 2 x 32 KB
  __shared__ __align__(16) char lds_b[2][BN * BK * 2];  // 2 x 32 KB

  int bid0 = blockIdx.x;
  int bid = (bid0 & 7) * (NBLK / 8) + (bid0 >> 3);  // XCD-chunked swizzle
  int bn = bid & 1;                                 // A-sharing pair adjacent
  int tm = bid >> 1;

  int g = -1, m_loc = 0, base = 0;
#pragma unroll
  for (int i = 0; i < GCNT; i++) {
    int ps = (sizes[i] + 127) & ~127;
    int tg = (ps + 255) >> 8;
    if (tm >= base && tm < base + tg) { g = i; m_loc = (tm - base) << 8; }
    base += tg;
  }
  if (g < 0) return;
  int size = sizes[g], off = offs[g], valid = size - m_loc;

  int t = threadIdx.x, lane = t & 63, wid = t >> 6;
  int wm = wid >> 2, wn = wid & 3, lr = lane & 15, q = lane >> 4;

  // A staging: thread t owns rows i*32 + (t>>4), fp32 cols (t&15)*4..+3
  int r0 = t >> 4, c16 = t & 15;
  int aoff[8];
#pragma unroll
  for (int i = 0; i < 8; i++) {
    int row = off + m_loc + i * 32 + r0;
    if (row >= T_ROWS) row = T_ROWS - 1;  // junk rows masked at store
    aoff[i] = row * KDIM + c16 * 4;
  }
  int a_wbyte = r0 * 128 + (((c16 >> 1) ^ (r0 & 7)) << 4) + (c16 & 1) * 8;

  const char* btbase = bt + ((size_t)g << 20);

  f32x4 acc[8][4];
#pragma unroll
  for (int i = 0; i < 8; i++)
#pragma unroll
    for (int j = 0; j < 4; j++) acc[i][j] = (f32x4){0.f, 0.f, 0.f, 0.f};
  f32x4 va[8];
  s16x8 af[4], bf0[4], bf1[4];

  auto issueA = [&](int kt, int h) {
#pragma unroll
    for (int i = 0; i < 4; i++)
      va[h * 4 + i] = *(const f32x4*)(a + aoff[h * 4 + i] + kt * BK);
  };
  auto writeA = [&](int c) {  // cvt: auto counted vmcnt via register dep
    char* db = (char*)lds_a[c] + a_wbyte;
#pragma unroll
    for (int i = 0; i < 8; i++) {
      s16x4 v;
#pragma unroll
      for (int e = 0; e < 4; e++) v[e] = f2bf(va[i][e]);
      *(s16x4*)(db + i * 4096) = v;
    }
  };
  auto issueB = [&](int kt, int c, int h) {
#pragma unroll
    for (int i = 0; i < 2; i++) {
      int wc = wid * 4 + h * 2 + i;          // wave-uniform chunk id
      int sub = wc >> 4;
      int cc = (wc & 15) * 64 + lane;
      const char* gsrc =
          btbase + (((size_t)((bn * 2 + sub) * 16 + kt)) << 14) + cc * 16;
      __builtin_amdgcn_global_load_lds(
          (gbl_u32*)gsrc, (lds_u32*)((char*)lds_b[c] + wc * 1024), 16, 0, 0);
    }
  };
  auto dsA = [&](int c, int half, int ks) {
#pragma unroll
    for (int i = 0; i < 4; i++) {
      int row = wm * 128 + (half * 4 + i) * 16 + lr;
      int slot = (ks * 4 + q) ^ (row & 7);
      af[i] = *(const s16x8*)((const char*)lds_a[c] + row * 128 + slot * 16);
    }
  };
  auto dsB = [&](int c, int ks, s16x8* bf) {
#pragma unroll
    for (int fn = 0; fn < 4; fn++) {
      int n = wn * 64 + fn * 16 + lr;
      int slot = (ks * 4 + q) ^ (n & 7);
      bf[fn] = *(const s16x8*)((const char*)lds_b[c] + (n >> 7) * 16384 +
                               (n & 127) * 128 + slot * 16);
    }
  };
  auto pbar = [&]() {
    __builtin_amdgcn_sched_barrier(0);
    __builtin_amdgcn_s_barrier();
  };
  auto mfmaQ = [&](const s16x8* bf, int fmb) {
    __builtin_amdgcn_s_setprio(1);
#pragma unroll
    for (int fm = 0; fm < 4; fm++)
#pragma unroll
      for (int fn = 0; fn < 4; fn++)
        acc[fmb + fm][fn] = __builtin_amdgcn_mfma_f32_16x16x32_bf16(
            af[fm], bf[fn], acc[fmb + fm][fn], 0, 0, 0);
    __builtin_amdgcn_s_setprio(0);
    __builtin_amdgcn_sched_barrier(0);
  };

  // prologue: A(0)->cvt->LDS0 (drains, ok here); B(0)->buf0; B(1)->buf1.
  issueA(0, 0);
  issueA(0, 1);
  writeA(0);                  // auto vmcnt for va
  issueB(0, 0, 0);
  issueB(0, 0, 1);            // B(0): 4 DMA (older)
  issueB(1, 1, 0);
  issueB(1, 1, 1);            // B(1): 4 DMA (newest, stays in flight)
  asm volatile("s_waitcnt vmcnt(4) lgkmcnt(0)" ::: "memory");
  __builtin_amdgcn_sched_barrier(0);
  __builtin_amdgcn_s_barrier();

  // main loop: fully unconditional -> precise compiler-counted waits
  for (int kt = 0; kt < KTILES - 2; kt++) {
    int cur = kt & 1, nxt = cur ^ 1;
    // ph0
    dsA(cur, 0, 0);
    dsB(cur, 0, bf0);
    issueA(kt + 1, 0);
    pbar();
    mfmaQ(bf0, 0);
    __builtin_amdgcn_s_barrier();
    // ph1
    dsA(cur, 0, 1);
    dsB(cur, 1, bf1);
    issueA(kt + 1, 1);
    pbar();
    mfmaQ(bf1, 0);
    __builtin_amdgcn_s_barrier();
    // ph2: lds_b[cur] reads all retired (pre-MFMA lgkm + barrier) -> reuse
    dsA(cur, 1, 0);
    issueB(kt + 2, cur, 0);
    pbar();
    mfmaQ(bf0, 4);
    __builtin_amdgcn_s_barrier();
    // ph3
    dsA(cur, 1, 1);
    issueB(kt + 2, cur, 1);
    pbar();
    mfmaQ(bf1, 4);
    __builtin_amdgcn_s_barrier();
    // ph4: cvt auto-waits vmcnt(4) (keeps B(kt+2) flying); publish ds_writes
    writeA(nxt);
    asm volatile("s_waitcnt lgkmcnt(0)" ::: "memory");
    __builtin_amdgcn_sched_barrier(0);
    __builtin_amdgcn_s_barrier();
  }

  // peeled kt = 14 (cur=0, nxt=1): issue A(15), no B issues
  {
    dsA(0, 0, 0); dsB(0, 0, bf0); issueA(15, 0);
    pbar(); mfmaQ(bf0, 0); __builtin_amdgcn_s_barrier();
    dsA(0, 0, 1); dsB(0, 1, bf1); issueA(15, 1);
    pbar(); mfmaQ(bf1, 0); __builtin_amdgcn_s_barrier();
    dsA(0, 1, 0); pbar(); mfmaQ(bf0, 4); __builtin_amdgcn_s_barrier();
    dsA(0, 1, 1); pbar(); mfmaQ(bf1, 4); __builtin_amdgcn_s_barrier();
    writeA(1);                 // auto-wait drains (tail only)
    asm volatile("s_waitcnt lgkmcnt(0)" ::: "memory");
    __builtin_amdgcn_sched_barrier(0);
    __builtin_amdgcn_s_barrier();
  }
  // peeled kt = 15 (cur=1): compute only
  {
    dsA(1, 0, 0); dsB(1, 0, bf0); pbar(); mfmaQ(bf0, 0);
    __builtin_amdgcn_s_barrier();
    dsA(1, 0, 1); dsB(1, 1, bf1); pbar(); mfmaQ(bf1, 0);
    __builtin_amdgcn_s_barrier();
    dsA(1, 1, 0); pbar(); mfmaQ(bf0, 4);
    __builtin_amdgcn_s_barrier();
    dsA(1, 1, 1); pbar(); mfmaQ(bf1, 4);
  }

  // epilogue: D frag col = lane&15, row = (lane>>4)*4 + j; masked rows
  size_t orow0 = (size_t)(off + m_loc);
#pragma unroll
  for (int fm = 0; fm < 8; fm++) {
#pragma unroll
    for (int j = 0; j < 4; j++) {
      int rm = wm * 128 + fm * 16 + q * 4 + j;
      if (rm < valid) {
        float* orow = out + (orow0 + rm) * NDIM + bn * BN + wn * 64 + lr;
#pragma unroll
        for (int fn = 0; fn < 4; fn++) orow[fn * 16] = acc[fm][fn][j];
      }
    }
  }
}

// ---------------------------------------------------------------------------
// Fallback (no workspace): round-2 2-phase kernel, B transposed in-kernel.
// ---------------------------------------------------------------------------
__global__ __launch_bounds__(512, 2) void gemm_fb(
    const float* __restrict__ a, const float* __restrict__ b,
    const int* __restrict__ sizes, const int* __restrict__ offs,
    float* __restrict__ out) {
  __shared__ __align__(16) short lds_a[2][BM * BK];
  __shared__ __align__(16) char lds_b[2][BN * BK * 2];

  int bid0 = blockIdx.x;
  int bid = (bid0 & 7) * (NBLK / 8) + (bid0 >> 3);
  int bn = bid & 1;
  int tm = bid >> 1;

  int g = -1, m_loc = 0, base = 0;
#pragma unroll
  for (int i = 0; i < GCNT; i++) {
    int ps = (sizes[i] + 127) & ~127;
    int tg = (ps + 255) >> 8;
    if (tm >= base && tm < base + tg) { g = i; m_loc = (tm - base) << 8; }
    base += tg;
  }
  if (g < 0) return;
  int size = sizes[g], off = offs[g], valid = size - m_loc;

  int t = threadIdx.x, lane = t & 63, wid = t >> 6;
  int wm = wid >> 2, wn = wid & 3, lr = lane & 15, q = lane >> 4;

  int r0 = t >> 4, c16 = t & 15;
  int aoff[8];
#pragma unroll
  for (int i = 0; i < 8; i++) {
    int row = off + m_loc + i * 32 + r0;
    if (row >= T_ROWS) row = T_ROWS - 1;
    aoff[i] = row * KDIM + c16 * 4;
  }
  int a_wbyte = r0 * 128 + (((c16 >> 1) ^ (r0 & 7)) << 4) + (c16 & 1) * 8;
  int fb_n = t >> 1, fb_kh = (t & 1) * 32;

  f32x4 acc[8][4];
#pragma unroll
  for (int i = 0; i < 8; i++)
#pragma unroll
    for (int j = 0; j < 4; j++) acc[i][j] = (f32x4){0.f, 0.f, 0.f, 0.f};
  f32x4 va[8];

  auto loadA = [&](int kt) {
#pragma unroll
    for (int i = 0; i < 8; i++) va[i] = *(const f32x4*)(a + aoff[i] + kt * BK);
  };
  auto writeA = [&](int c) {
    char* db = (char*)lds_a[c] + a_wbyte;
#pragma unroll
    for (int i = 0; i < 8; i++) {
      s16x4 v;
#pragma unroll
      for (int e = 0; e < 4; e++) v[e] = f2bf(va[i][e]);
      *(s16x4*)(db + i * 4096) = v;
    }
  };
  auto stageB = [&](int kt, int c) {
    const float* p = b + (size_t)g * KDIM * NDIM +
                     (size_t)(kt * BK + fb_kh) * NDIM + bn * BN + fb_n;
    float vals[32];
#pragma unroll
    for (int i = 0; i < 32; i++) vals[i] = p[(size_t)i * NDIM];
    int nn = fb_n & 127;
    char* lb = (char*)lds_b[c] + (fb_n >> 7) * 16384 + nn * 128;
#pragma unroll
    for (int i8 = 0; i8 < 4; i8++) {
      int slot = (fb_kh >> 3) + i8;
      s16x8 v;
#pragma unroll
      for (int e = 0; e < 8; e++) v[e] = f2bf(vals[i8 * 8 + e]);
      *(s16x8*)(lb + (((slot ^ (nn & 7))) << 4)) = v;
    }
  };
  auto compute = [&](int c) {
#pragma unroll
    for (int ks = 0; ks < 2; ks++) {
      s16x8 af[8], bfr[4];
#pragma unroll
      for (int fm = 0; fm < 8; fm++) {
        int row = wm * 128 + fm * 16 + lr;
        int slot = (ks * 4 + q) ^ (row & 7);
        af[fm] = *(const s16x8*)((const char*)lds_a[c] + row * 128 + slot * 16);
      }
#pragma unroll
      for (int fn = 0; fn < 4; fn++) {
        int n = wn * 64 + fn * 16 + lr;
        int slot = (ks * 4 + q) ^ (n & 7);
        bfr[fn] = *(const s16x8*)((const char*)lds_b[c] + (n >> 7) * 16384 +
                                  (n & 127) * 128 + slot * 16);
      }
#pragma unroll
      for (int fm = 0; fm < 8; fm++)
#pragma unroll
        for (int fn = 0; fn < 4; fn++)
          acc[fm][fn] = __builtin_amdgcn_mfma_f32_16x16x32_bf16(
              af[fm], bfr[fn], acc[fm][fn], 0, 0, 0);
    }
  };

  loadA(0);
  stageB(0, 0);
  writeA(0);
  __syncthreads();
  int cur = 0;
  for (int kt = 0; kt < KTILES; kt++) {
    if (kt + 1 < KTILES) loadA(kt + 1);
    compute(cur);
    if (kt + 1 < KTILES) {
      stageB(kt + 1, cur ^ 1);
      writeA(cur ^ 1);
      __syncthreads();
      cur ^= 1;
    }
  }
  size_t orow0 = (size_t)(off + m_loc);
#pragma unroll
  for (int fm = 0; fm < 8; fm++) {
#pragma unroll
    for (int j = 0; j < 4; j++) {
      int rm = wm * 128 + fm * 16 + q * 4 + j;
      if (rm < valid) {
        float* orow = out + (orow0 + rm) * NDIM + bn * BN + wn * 64 + lr;
#pragma unroll
        for (int fn = 0; fn < 4; fn++) orow[fn * 16] = acc[fm][fn][j];
      }
    }
  }
}

extern "C" void kernel_launch(void* const* d_in, const int* in_sizes, int n_in,
                              void* d_out, int out_size, void* d_ws,
                              size_t ws_size, hipStream_t stream) {
  const float* a = (const float*)d_in[0];
  const float* b = (const float*)d_in[1];
  const int* sizes = (const int*)d_in[2];
  const int* offs = (const int*)d_in[3];
  float* out = (float*)d_out;

  const size_t bt_bytes = (size_t)GCNT * KDIM * NDIM * 2;  // 64 MB
  if (ws_size >= bt_bytes) {
    bt_kernel<<<GCNT * 64, 256, 0, stream>>>(b, (char*)d_ws);
    gemm8<<<NBLK, 512, 0, stream>>>(a, (const char*)d_ws, sizes, offs, out);
  } else {
    gemm_fb<<<NBLK, 512, 0, stream>>>(a, b, sizes, offs, out);
  }
}

// Round 8
// 339.023 us; speedup vs baseline: 1.2574x; 1.0363x over previous
//
#include <hip/hip_runtime.h>
#include <hip/hip_bf16.h>
#include <stdint.h>

#define T_ROWS 131072
#define GCNT   64
#define KDIM   1024
#define NDIM   512
#define BM     128
#define BN     128
#define BK     64
#define KTILES (KDIM / BK)     // 16
#define MT_MAX 1088            // upper bound on 128-row tiles (~1055 actual)
#define NBLK   (MT_MAX * 4)    // 4352 blocks, /8 = 544 (XCD swizzle exact)

typedef __attribute__((ext_vector_type(4))) float f32x4;
typedef __attribute__((ext_vector_type(8))) short s16x8;
typedef __attribute__((ext_vector_type(4))) short s16x4;
typedef __attribute__((address_space(3))) unsigned int lds_u32;
typedef const __attribute__((address_space(1))) unsigned int gbl_u32;

static __device__ __forceinline__ short f2bf(float f) {
  __hip_bfloat16 h = __float2bfloat16(f);
  return __builtin_bit_cast(short, h);
}

// ---------------------------------------------------------------------------
// Pre-pass: b [G][K][N] fp32 -> bt: per (g, nt128, kt) 16KB bf16 tile images,
// layout [G][4][16][16384B]. Image byte for B[k][n] (k in [0,64), n in
// [0,128)):  n*128 + (((k>>3) ^ (n&7))<<4) + (k&7)*2   (bank swizzle baked).
// ---------------------------------------------------------------------------
__global__ __launch_bounds__(256) void bt_kernel(const float* __restrict__ b,
                                                 char* __restrict__ bt) {
  __shared__ short lt[64 * 130];
  int bid = blockIdx.x;               // g*64 + nt*16 + kt
  int kt = bid & 15, nt = (bid >> 4) & 3, g = bid >> 6;
  int t = threadIdx.x;
  const float* src = b + ((size_t)(g * KDIM + kt * BK)) * NDIM + nt * 128;
#pragma unroll
  for (int i = 0; i < 32; i++) {
    int idx = i * 256 + t;
    int kk = idx >> 7, nn = idx & 127;
    lt[kk * 130 + nn] = f2bf(src[(size_t)kk * NDIM + nn]);
  }
  __syncthreads();
  char* dst = bt + ((size_t)bid << 14);
#pragma unroll
  for (int j = 0; j < 4; j++) {
    int chunk = j * 256 + t;
    int n = chunk >> 3;
    int slot = (chunk & 7) ^ (n & 7);
    s16x8 v;
#pragma unroll
    for (int i = 0; i < 8; i++) v[i] = lt[(slot * 8 + i) * 130 + n];
    *(s16x8*)(dst + (size_t)chunk * 16) = v;
  }
}

// ---------------------------------------------------------------------------
// Grouped GEMM: 128x128 tile, 4 waves, BK=64, 64KB LDS -> 2 blocks/CU.
// Raw-barrier pipeline, ONE barrier per K-tile, counted vmcnt:
//   stageB(kt+1 -> nxt)  [4 DMA, oldest this iter; sched_barrier pins order]
//   loadA(kt+2 -> bank)  [8 fp32x4 loads, stay in flight across 2 tiles]
//   compute(cur)         [ds_read + MFMA, compiler-counted lgkm]
//   writeA(nxt, bank')   [cvt auto-waits counted vmcnt: bank' is oldest]
//   s_waitcnt vmcnt(8)   [retire B(kt+1) DMAs; A(kt+2) keeps flying]
//   lgkmcnt(0); s_barrier
// vmcnt NEVER drains to 0 in the main loop; no __syncthreads anywhere.
// ---------------------------------------------------------------------------
__global__ __launch_bounds__(256, 2) void gemm2(
    const float* __restrict__ a, const char* __restrict__ bt,
    const int* __restrict__ sizes, const int* __restrict__ offs,
    float* __restrict__ out) {
  __shared__ __align__(16) short lds_a[2][BM * BK];     // 2 x 16 KB
  __shared__ __align__(16) char lds_b[2][BN * BK * 2];  // 2 x 16 KB

  int bid0 = blockIdx.x;
  int bid = (bid0 & 7) * (NBLK / 8) + (bid0 >> 3);  // XCD-chunked swizzle
  int bn = bid & 3;      // bn fastest: 4 blocks sharing an A panel adjacent
  int tm = bid >> 2;

  int g = -1, m_loc = 0, base = 0;
#pragma unroll
  for (int i = 0; i < GCNT; i++) {
    int tg = ((sizes[i] + 127) & ~127) >> 7;
    if (tm >= base && tm < base + tg) { g = i; m_loc = (tm - base) << 7; }
    base += tg;
  }
  if (g < 0) return;
  int size = sizes[g], off = offs[g], valid = size - m_loc;

  int t = threadIdx.x, lane = t & 63, wid = t >> 6;
  int wm = wid >> 1, wn = wid & 1, lr = lane & 15, q = lane >> 4;

  // A staging: thread t owns rows i*16 + (t>>4), 16B chunk (t&15) of each row
  int r0 = t >> 4, c16 = t & 15;
  int aoff[8];
#pragma unroll
  for (int i = 0; i < 8; i++) {
    int row = off + m_loc + i * 16 + r0;
    if (row >= T_ROWS) row = T_ROWS - 1;  // junk rows masked at store
    aoff[i] = row * KDIM + c16 * 4;
  }
  int a_wbyte = r0 * 128 + (((c16 >> 1) ^ (r0 & 7)) << 4) + (c16 & 1) * 8;

  const char* btimg = bt + ((size_t)((g << 6) + (bn << 4)) << 14);

  f32x4 acc[4][4];
#pragma unroll
  for (int i = 0; i < 4; i++)
#pragma unroll
    for (int j = 0; j < 4; j++) acc[i][j] = (f32x4){0.f, 0.f, 0.f, 0.f};
  f32x4 va0[8], va1[8];   // two named A fp32 banks (depth-2 pipeline)

  auto loadA = [&](int kt, f32x4 (&va)[8]) {
#pragma unroll
    for (int i = 0; i < 8; i++)
      va[i] = *(const f32x4*)(a + aoff[i] + kt * BK);
  };
  auto writeA = [&](int c, f32x4 (&va)[8]) {  // cvt auto-waits counted vmcnt
    char* db = (char*)lds_a[c] + a_wbyte;
#pragma unroll
    for (int i = 0; i < 8; i++) {
      s16x4 v;
#pragma unroll
      for (int e = 0; e < 4; e++) v[e] = f2bf(va[i][e]);
      *(s16x4*)(db + i * 2048) = v;
    }
  };
  auto stageB = [&](int kt, int c) {
#pragma unroll
    for (int i = 0; i < 4; i++) {
      int wc = wid * 4 + i;                 // wave-uniform 1KB chunk, 0..15
      int cc = wc * 64 + lane;
      const char* gsrc = btimg + ((size_t)kt << 14) + (size_t)cc * 16;
      __builtin_amdgcn_global_load_lds(
          (gbl_u32*)gsrc, (lds_u32*)((char*)lds_b[c] + wc * 1024), 16, 0, 0);
    }
  };
  auto compute = [&](int c) {
#pragma unroll
    for (int ks = 0; ks < 2; ks++) {
      s16x8 af[4], bf[4];
#pragma unroll
      for (int fm = 0; fm < 4; fm++) {
        int row = wm * 64 + fm * 16 + lr;
        int slot = (ks * 4 + q) ^ (row & 7);
        af[fm] = *(const s16x8*)((const char*)lds_a[c] + row * 128 + slot * 16);
      }
#pragma unroll
      for (int fn = 0; fn < 4; fn++) {
        int n = wn * 64 + fn * 16 + lr;
        int slot = (ks * 4 + q) ^ (n & 7);
        bf[fn] = *(const s16x8*)((const char*)lds_b[c] + n * 128 + slot * 16);
      }
      __builtin_amdgcn_s_setprio(1);
#pragma unroll
      for (int fm = 0; fm < 4; fm++)
#pragma unroll
        for (int fn = 0; fn < 4; fn++)
          acc[fm][fn] = __builtin_amdgcn_mfma_f32_16x16x32_bf16(
              af[fm], bf[fn], acc[fm][fn], 0, 0, 0);
      __builtin_amdgcn_s_setprio(0);
    }
  };

#define TILE_BODY(KT, CUR, NXT, VA_WR, VA_LD, MOREA)                         \
  {                                                                          \
    stageB((KT) + 1, (NXT));               /* 4 DMA, oldest this iter */     \
    __builtin_amdgcn_sched_barrier(0);                                       \
    if (MOREA) loadA((KT) + 2, VA_LD);     /* 8 loads, newer */              \
    __builtin_amdgcn_sched_barrier(0);                                       \
    compute(CUR);                                                            \
    writeA((NXT), VA_WR);                                                    \
    if (MOREA)                                                               \
      asm volatile("s_waitcnt vmcnt(8) lgkmcnt(0)" ::: "memory");            \
    else                                                                     \
      asm volatile("s_waitcnt vmcnt(0) lgkmcnt(0)" ::: "memory");            \
    __builtin_amdgcn_sched_barrier(0);                                       \
    __builtin_amdgcn_s_barrier();                                            \
  }

  // prologue: A(0)->LDS0 (drains, ok once); B(0) DMA; A(1) in flight.
  loadA(0, va0);
  writeA(0, va0);                       // auto vmcnt for va0
  stageB(0, 0);                         // 4 DMA (older)
  __builtin_amdgcn_sched_barrier(0);
  loadA(1, va1);                        // 8 loads (newer), stay in flight
  asm volatile("s_waitcnt vmcnt(8) lgkmcnt(0)" ::: "memory");
  __builtin_amdgcn_sched_barrier(0);
  __builtin_amdgcn_s_barrier();

  // main loop kt = 0..13, unrolled x2 for compile-time bank/buffer names
  for (int kt2 = 0; kt2 < KTILES - 2; kt2 += 2) {
    TILE_BODY(kt2, 0, 1, va1, va0, (kt2 + 2 < KTILES));      // even kt
    TILE_BODY(kt2 + 1, 1, 0, va0, va1, (kt2 + 3 < KTILES));  // odd kt
  }
  // peeled kt = 14: stage B(15), write A(15) (va1), drain (tail only)
  TILE_BODY(14, 0, 1, va1, va0, false);
  // peeled kt = 15: compute only
  compute(1);
#undef TILE_BODY

  // epilogue: D frag col = lane&15, row = (lane>>4)*4 + j; masked rows
  size_t orow0 = (size_t)(off + m_loc);
#pragma unroll
  for (int fm = 0; fm < 4; fm++) {
#pragma unroll
    for (int j = 0; j < 4; j++) {
      int rm = wm * 64 + fm * 16 + q * 4 + j;
      if (rm < valid) {
        float* orow = out + (orow0 + rm) * NDIM + bn * BN + wn * 64 + lr;
#pragma unroll
        for (int fn = 0; fn < 4; fn++) orow[fn * 16] = acc[fm][fn][j];
      }
    }
  }
}

// ---------------------------------------------------------------------------
// Fallback (no workspace): round-6 2-phase kernel, B transposed in-kernel.
// ---------------------------------------------------------------------------
__global__ __launch_bounds__(256, 2) void gemm_fb(
    const float* __restrict__ a, const float* __restrict__ b,
    const int* __restrict__ sizes, const int* __restrict__ offs,
    float* __restrict__ out) {
  __shared__ __align__(16) short lds_a[2][BM * BK];
  __shared__ __align__(16) char lds_b[2][BN * BK * 2];

  int bid0 = blockIdx.x;
  int bid = (bid0 & 7) * (NBLK / 8) + (bid0 >> 3);
  int bn = bid & 3;
  int tm = bid >> 2;

  int g = -1, m_loc = 0, base = 0;
#pragma unroll
  for (int i = 0; i < GCNT; i++) {
    int tg = ((sizes[i] + 127) & ~127) >> 7;
    if (tm >= base && tm < base + tg) { g = i; m_loc = (tm - base) << 7; }
    base += tg;
  }
  if (g < 0) return;
  int size = sizes[g], off = offs[g], valid = size - m_loc;

  int t = threadIdx.x, lane = t & 63, wid = t >> 6;
  int wm = wid >> 1, wn = wid & 1, lr = lane & 15, q = lane >> 4;

  int r0 = t >> 4, c16 = t & 15;
  int aoff[8];
#pragma unroll
  for (int i = 0; i < 8; i++) {
    int row = off + m_loc + i * 16 + r0;
    if (row >= T_ROWS) row = T_ROWS - 1;
    aoff[i] = row * KDIM + c16 * 4;
  }
  int a_wbyte = r0 * 128 + (((c16 >> 1) ^ (r0 & 7)) << 4) + (c16 & 1) * 8;
  int fb_n = t >> 1, fb_kh = (t & 1) * 32;

  f32x4 acc[4][4];
#pragma unroll
  for (int i = 0; i < 4; i++)
#pragma unroll
    for (int j = 0; j < 4; j++) acc[i][j] = (f32x4){0.f, 0.f, 0.f, 0.f};
  f32x4 va[8];

  auto loadA = [&](int kt) {
#pragma unroll
    for (int i = 0; i < 8; i++) va[i] = *(const f32x4*)(a + aoff[i] + kt * BK);
  };
  auto writeA = [&](int c) {
    char* db = (char*)lds_a[c] + a_wbyte;
#pragma unroll
    for (int i = 0; i < 8; i++) {
      s16x4 v;
#pragma unroll
      for (int e = 0; e < 4; e++) v[e] = f2bf(va[i][e]);
      *(s16x4*)(db + i * 2048) = v;
    }
  };
  auto stageB = [&](int kt, int c) {
    const float* p = b + (size_t)g * KDIM * NDIM +
                     (size_t)(kt * BK + fb_kh) * NDIM + bn * BN + fb_n;
    float vals[32];
#pragma unroll
    for (int i = 0; i < 32; i++) vals[i] = p[(size_t)i * NDIM];
    char* lb = (char*)lds_b[c] + fb_n * 128;
#pragma unroll
    for (int i8 = 0; i8 < 4; i8++) {
      int slot = (fb_kh >> 3) + i8;
      s16x8 v;
#pragma unroll
      for (int e = 0; e < 8; e++) v[e] = f2bf(vals[i8 * 8 + e]);
      *(s16x8*)(lb + ((slot ^ (fb_n & 7)) << 4)) = v;
    }
  };
  auto compute = [&](int c) {
#pragma unroll
    for (int ks = 0; ks < 2; ks++) {
      s16x8 af[4], bf[4];
#pragma unroll
      for (int fm = 0; fm < 4; fm++) {
        int row = wm * 64 + fm * 16 + lr;
        int slot = (ks * 4 + q) ^ (row & 7);
        af[fm] = *(const s16x8*)((const char*)lds_a[c] + row * 128 + slot * 16);
      }
#pragma unroll
      for (int fn = 0; fn < 4; fn++) {
        int n = wn * 64 + fn * 16 + lr;
        int slot = (ks * 4 + q) ^ (n & 7);
        bf[fn] = *(const s16x8*)((const char*)lds_b[c] + n * 128 + slot * 16);
      }
#pragma unroll
      for (int fm = 0; fm < 4; fm++)
#pragma unroll
        for (int fn = 0; fn < 4; fn++)
          acc[fm][fn] = __builtin_amdgcn_mfma_f32_16x16x32_bf16(
              af[fm], bf[fn], acc[fm][fn], 0, 0, 0);
    }
  };

  loadA(0);
  stageB(0, 0);
  writeA(0);
  __syncthreads();
  for (int kt = 0; kt < KTILES; kt++) {
    int cur = kt & 1, nxt = cur ^ 1;
    bool more = (kt + 1 < KTILES);
    if (more) loadA(kt + 1);
    compute(cur);
    if (more) {
      stageB(kt + 1, nxt);
      writeA(nxt);
      __syncthreads();
    }
  }
  size_t orow0 = (size_t)(off + m_loc);
#pragma unroll
  for (int fm = 0; fm < 4; fm++) {
#pragma unroll
    for (int j = 0; j < 4; j++) {
      int rm = wm * 64 + fm * 16 + q * 4 + j;
      if (rm < valid) {
        float* orow = out + (orow0 + rm) * NDIM + bn * BN + wn * 64 + lr;
#pragma unroll
        for (int fn = 0; fn < 4; fn++) orow[fn * 16] = acc[fm][fn][j];
      }
    }
  }
}

extern "C" void kernel_launch(void* const* d_in, const int* in_sizes, int n_in,
                              void* d_out, int out_size, void* d_ws,
                              size_t ws_size, hipStream_t stream) {
  const float* a = (const float*)d_in[0];
  const float* b = (const float*)d_in[1];
  const int* sizes = (const int*)d_in[2];
  const int* offs = (const int*)d_in[3];
  float* out = (float*)d_out;

  const size_t bt_bytes = (size_t)GCNT * KDIM * NDIM * 2;  // 64 MB
  if (ws_size >= bt_bytes) {
    bt_kernel<<<GCNT * 64, 256, 0, stream>>>(b, (char*)d_ws);
    gemm2<<<NBLK, 256, 0, stream>>>(a, (const char*)d_ws, sizes, offs, out);
  } else {
    gemm_fb<<<NBLK, 256, 0, stream>>>(a, b, sizes, offs, out);
  }
}